// Round 4
// baseline (662.451 us; speedup 1.0000x reference)
//
#include <hip/hip_runtime.h>
#include <math.h>

// Problem constants
#define B_  32
#define S_  2048
#define E_  1024   // 2*HIDDEN
#define A_  512    // ATT
#define H_  512

#define MB   64              // rows (s) per fused block
#define NCH  (S_ / MB)       // 32 chunks per batch row
#define KT   32              // K per MFMA sub-step
#define BK   64              // K per barrier period (2 sub-steps)
#define NP   (E_ / BK)       // 16 periods

typedef __bf16 bf16;
typedef __attribute__((ext_vector_type(8))) __bf16 bf16x8;
typedef __attribute__((ext_vector_type(4))) float  f32x4;

__device__ __forceinline__ float fast_tanh(float x) {
    x = fminf(fmaxf(x, -15.f), 15.f);
    const float e = __expf(2.f * x);
    return (e - 1.f) / (e + 1.f);
}

// ---------------------------------------------------------------------------
// prep kernel: blocks 0..127  : split W_enc into bf16 hi/lo, transposed [a][k]
//              blocks 128..383: dec_att k-split partials dp[seg][b][a]
// ---------------------------------------------------------------------------
__global__ __launch_bounds__(256)
void prep_kernel(const float* __restrict__ Wenc,
                 const float* __restrict__ dh,
                 const float* __restrict__ Wdec,
                 const float* __restrict__ bdec,
                 bf16* __restrict__ Whi, bf16* __restrict__ Wlo,
                 float* __restrict__ dp) {
    const int t = threadIdx.x;
    if (blockIdx.x < 128) {
        __shared__ float tile[64][65];
        const int kb = blockIdx.x >> 3;      // 0..15
        const int ab = blockIdx.x & 7;       // 0..7
        const int k0 = kb * 64, a0 = ab * 64;
#pragma unroll
        for (int p = 0; p < 8; ++p) {
            const int kk = p * 8 + (t >> 5);
            const int aa = (t & 31) * 2;
            const float2 v = *(const float2*)&Wenc[(size_t)(k0 + kk) * A_ + a0 + aa];
            tile[kk][aa]     = v.x;
            tile[kk][aa + 1] = v.y;
        }
        __syncthreads();
        const int aa  = t >> 2;
        const int kk0 = (t & 3) * 16;
        bf16x8 hv0, hv1, lv0, lv1;
#pragma unroll
        for (int j = 0; j < 16; ++j) {
            const float x = tile[kk0 + j][aa];
            const bf16 h = (bf16)x;
            const bf16 l = (bf16)(x - (float)h);
            if (j < 8) { hv0[j] = h; lv0[j] = l; }
            else       { hv1[j - 8] = h; lv1[j - 8] = l; }
        }
        bf16* dh_ = Whi + (size_t)(a0 + aa) * E_ + k0 + kk0;
        bf16* dl_ = Wlo + (size_t)(a0 + aa) * E_ + k0 + kk0;
        *(bf16x8*)dh_ = hv0; *((bf16x8*)dh_ + 1) = hv1;
        *(bf16x8*)dl_ = lv0; *((bf16x8*)dl_ + 1) = lv1;
    } else {
        __shared__ float dhl[64];
        const int idx = blockIdx.x - 128;
        const int b   = idx >> 3;
        const int seg = idx & 7;
        if (t < 64) dhl[t] = dh[b * H_ + seg * 64 + t];
        __syncthreads();
        const int a0 = t, a1 = t + 256;
        float acc0 = 0.f, acc1 = 0.f;
        const float* Wrow = Wdec + (size_t)(seg * 64) * A_;
#pragma unroll 8
        for (int h = 0; h < 64; ++h) {
            const float s = dhl[h];
            acc0 += s * Wrow[h * A_ + a0];
            acc1 += s * Wrow[h * A_ + a1];
        }
        if (seg == 0) { acc0 += bdec[a0]; acc1 += bdec[a1]; }
        dp[(size_t)(seg * B_ + b) * A_ + a0] = acc0;
        dp[(size_t)(seg * B_ + b) * A_ + a1] = acc1;
    }
}

// ---------------------------------------------------------------------------
// Fused kernel v4: MB=64 tile, 512 threads / 8 waves, wave owns 64x64
// (acc[4][4] = 64 AGPR). Total regs capped at 128 (__launch_bounds__(512,4))
// -> TWO blocks co-resident per CU, each with its OWN barrier group. The two
// groups run anti-phase, so one block's MFMA burst covers the other block's
// ds_read/stage/barrier phase (v1-v3 were single-group lockstep: every pipe
// <=40% busy yet wall = sum of phases). Barrier once per BK=64 (16 total).
// W global->reg JIT per sub-step (L2-resident); A fp32 prefetched one period
// ahead, converted to bf16 hi/lo into the LDS double buffer.
// ---------------------------------------------------------------------------
__global__ __launch_bounds__(512, 4)
void fused_kernel(const float* __restrict__ enc,     // [B,S,E] fp32
                  const int*   __restrict__ masks,   // [B,S]
                  const bf16*  __restrict__ Whi_g,   // [A,E] bf16 (W^T hi)
                  const bf16*  __restrict__ Wlo_g,   // [A,E] bf16 (W^T lo)
                  const float* __restrict__ benc,    // [A]
                  const float* __restrict__ Watt,    // [A]
                  const float* __restrict__ batt,    // [1]
                  const float* __restrict__ dp,      // [8,B,A] dec_att parts
                  float* __restrict__ pm,            // [B*NCH]
                  float* __restrict__ pl,            // [B*NCH]
                  float* __restrict__ pctx) {        // [B*NCH, A]
    __shared__ union {
        struct {
            __align__(16) bf16 Ab[2][2][2][2048];     // [buf][sub][hi/lo][64x32] = 32 KB
        } k;
        struct {
            float decl[A_], wattl[A_], bencl[A_];     // 6 KB
            float red[MB * 9];                        // 2.25 KB
            float score[MB], p[MB];                   // 0.5 KB
            int   mask[MB];                           // 0.25 KB
        } e;
    } sm;                                             // 32 KB

    const int t    = threadIdx.x;
    const int wv   = t >> 6;      // wave 0..7
    const int L    = t & 63;      // lane
    const int quad = L >> 4;      // 0..3
    const int colL = L & 15;      // 0..15
    const int b    = blockIdx.x >> 5;
    const int ch   = blockIdx.x & 31;
    const int s0   = ch * MB;

    const float* encB = enc + ((size_t)(b * S_ + s0)) * E_;

    f32x4 acc[4][4];
#pragma unroll
    for (int mt = 0; mt < 4; ++mt)
#pragma unroll
        for (int nt = 0; nt < 4; ++nt) acc[mt][nt] = (f32x4){0.f, 0.f, 0.f, 0.f};

    // ---- A staging: thread t -> row t>>3 (0..63), 8 consecutive k at (t&7)*8
    const int arow = t >> 3;
    const int k0   = (t & 7) * 8;           // 0..56
    const int asub = k0 >> 5;               // sub-step 0/1
    const int akq  = (k0 & 31) >> 3;        // k-quad within sub-step
    const int a_wr = (arow >> 4) * 512 + akq * 128 +
                     (((arow & 15) ^ (akq << 2)) * 8);     // swizzled elem off
    const float* aptr = encB + (size_t)arow * E_ + k0;
    const int a_rd = quad * 128 + ((colL ^ (quad << 2)) * 8);

    // ---- per-lane W base: row (wv*64 + nt*16 + colL), k-chunk quad*8
    const size_t woff = (size_t)(wv * 64 + colL) * E_ + quad * 8;
    const bf16* wHi = Whi_g + woff;
    const bf16* wLo = Wlo_g + woff;

    // ================= prologue: stage A period 0 into buf 0 =================
    {
        const float4 c0 = *(const float4*)(aptr);
        const float4 c1 = *(const float4*)(aptr + 4);
        const float xs[8] = {c0.x, c0.y, c0.z, c0.w, c1.x, c1.y, c1.z, c1.w};
        bf16x8 hv, lv;
#pragma unroll
        for (int j = 0; j < 8; ++j) {
            const bf16 h = (bf16)xs[j];
            hv[j] = h; lv[j] = (bf16)(xs[j] - (float)h);
        }
        *(bf16x8*)&sm.k.Ab[0][asub][0][a_wr] = hv;
        *(bf16x8*)&sm.k.Ab[0][asub][1][a_wr] = lv;
    }
    asm volatile("s_waitcnt lgkmcnt(0)" ::: "memory");
    __builtin_amdgcn_s_barrier();
    asm volatile("" ::: "memory");

    // One K sub-step: load W frags (JIT, L2-hit) + 48 MFMAs on LDS buf[buf][SUB_]
#define KKBLOCK(KG_, SUB_)                                                     \
    {                                                                          \
        bf16x8 bh[4], bl[4];                                                   \
        _Pragma("unroll")                                                      \
        for (int nt = 0; nt < 4; ++nt) {                                       \
            bh[nt] = *(const bf16x8*)(wHi + (size_t)nt * (16 * E_) + (KG_));   \
            bl[nt] = *(const bf16x8*)(wLo + (size_t)nt * (16 * E_) + (KG_));   \
        }                                                                      \
        const bf16* Ahi_ = &sm.k.Ab[buf][SUB_][0][0];                          \
        const bf16* Alo_ = &sm.k.Ab[buf][SUB_][1][0];                          \
        _Pragma("unroll")                                                      \
        for (int mt = 0; mt < 4; ++mt) {                                       \
            const bf16x8 ah = *(const bf16x8*)&Ahi_[mt * 512 + a_rd];          \
            const bf16x8 al = *(const bf16x8*)&Alo_[mt * 512 + a_rd];          \
            _Pragma("unroll")                                                  \
            for (int nt = 0; nt < 4; ++nt) {                                   \
                acc[mt][nt] = __builtin_amdgcn_mfma_f32_16x16x32_bf16(         \
                    ah, bh[nt], acc[mt][nt], 0, 0, 0);                         \
                acc[mt][nt] = __builtin_amdgcn_mfma_f32_16x16x32_bf16(         \
                    al, bh[nt], acc[mt][nt], 0, 0, 0);                         \
                acc[mt][nt] = __builtin_amdgcn_mfma_f32_16x16x32_bf16(         \
                    ah, bl[nt], acc[mt][nt], 0, 0, 0);                         \
            }                                                                  \
        }                                                                      \
    }

    // ================= K loop: 16 periods, one barrier each =================
    for (int p = 0; p < NP; ++p) {
        const int buf = p & 1;
        const bool more = (p + 1 < NP);
        float4 c0, c1;
        if (more) {
            const float* np = aptr + (size_t)(p + 1) * BK;
            c0 = *(const float4*)(np);
            c1 = *(const float4*)(np + 4);
        }
        KKBLOCK(p * BK, 0);
        if (more) {   // convert + write A[p+1] into the other buffer
            const float xs[8] = {c0.x, c0.y, c0.z, c0.w, c1.x, c1.y, c1.z, c1.w};
            bf16x8 hv, lv;
#pragma unroll
            for (int j = 0; j < 8; ++j) {
                const bf16 h = (bf16)xs[j];
                hv[j] = h; lv[j] = (bf16)(xs[j] - (float)h);
            }
            *(bf16x8*)&sm.k.Ab[buf ^ 1][asub][0][a_wr] = hv;
            *(bf16x8*)&sm.k.Ab[buf ^ 1][asub][1][a_wr] = lv;
        }
        KKBLOCK(p * BK + KT, 1);
        asm volatile("s_waitcnt lgkmcnt(0)" ::: "memory");
        __builtin_amdgcn_s_barrier();
        asm volatile("" ::: "memory");
    }
#undef KKBLOCK

    // ================= epilogue =================
    __syncthreads();   // all K-loop LDS traffic done before union repurposed
    {
        float d = 0.f;
#pragma unroll
        for (int g = 0; g < 8; ++g) d += dp[(size_t)(g * B_ + b) * A_ + t];
        sm.e.decl[t]  = d;                 // t < 512 == A_
        sm.e.wattl[t] = Watt[t];
        sm.e.bencl[t] = benc[t];
        if (t < MB) sm.e.mask[t] = masks[(size_t)b * S_ + s0 + t];
    }
    __syncthreads();

    float sp[4][4];
#pragma unroll
    for (int mt = 0; mt < 4; ++mt)
#pragma unroll
        for (int r = 0; r < 4; ++r) sp[mt][r] = 0.f;

#pragma unroll
    for (int nt = 0; nt < 4; ++nt) {
        const int cg = wv * 64 + nt * 16 + colL;
        const float bv  = sm.e.bencl[cg];
        const float dv  = sm.e.decl[cg];
        const float wav = sm.e.wattl[cg];
#pragma unroll
        for (int mt = 0; mt < 4; ++mt)
#pragma unroll
            for (int r = 0; r < 4; ++r) {
                const float ea = acc[mt][nt][r] + bv;
                acc[mt][nt][r] = ea;
                sp[mt][r] += fast_tanh(ea + dv) * wav;
            }
    }
#pragma unroll
    for (int d = 1; d < 16; d <<= 1)
#pragma unroll
        for (int mt = 0; mt < 4; ++mt)
#pragma unroll
            for (int r = 0; r < 4; ++r)
                sp[mt][r] += __shfl_xor(sp[mt][r], d);
    if (colL == 0) {
#pragma unroll
        for (int mt = 0; mt < 4; ++mt)
#pragma unroll
            for (int r = 0; r < 4; ++r)
                sm.e.red[(mt * 16 + quad * 4 + r) * 9 + wv] = sp[mt][r];
    }
    __syncthreads();

    if (t < MB) {
        float s = 0.f;
#pragma unroll
        for (int j = 0; j < 8; ++j) s += sm.e.red[t * 9 + j];
        sm.e.score[t] = s + batt[0];
    }
    __syncthreads();

    float m_loc = -1e30f;
    for (int r = 0; r < MB; ++r)
        if (!sm.e.mask[r]) m_loc = fmaxf(m_loc, sm.e.score[r]);
    if (t < MB) sm.e.p[t] = sm.e.mask[t] ? 0.f : __expf(sm.e.score[t] - m_loc);
    __syncthreads();

    float ctxl[4] = {0.f, 0.f, 0.f, 0.f};
#pragma unroll
    for (int mt = 0; mt < 4; ++mt)
#pragma unroll
        for (int r = 0; r < 4; ++r) {
            const float p = sm.e.p[mt * 16 + quad * 4 + r];
#pragma unroll
            for (int nt = 0; nt < 4; ++nt) ctxl[nt] += p * acc[mt][nt][r];
        }
#pragma unroll
    for (int nt = 0; nt < 4; ++nt) {
        ctxl[nt] += __shfl_xor(ctxl[nt], 16);
        ctxl[nt] += __shfl_xor(ctxl[nt], 32);
    }
    if (quad == 0) {
#pragma unroll
        for (int nt = 0; nt < 4; ++nt)
            pctx[(size_t)blockIdx.x * A_ + wv * 64 + nt * 16 + colL] = ctxl[nt];
    }
    if (t == 0) {
        float l = 0.f;
        for (int r = 0; r < MB; ++r) l += sm.e.p[r];
        pm[blockIdx.x] = m_loc;
        pl[blockIdx.x] = l;
    }
}

// ---------------------------------------------------------------------------
// Combine: merge NCH chunk partials per batch row
// ---------------------------------------------------------------------------
__global__ __launch_bounds__(512)
void combine_kernel(const float* __restrict__ pm,
                    const float* __restrict__ pl,
                    const float* __restrict__ pctx,
                    float* __restrict__ out) {
    const int b = blockIdx.x;
    const int t = threadIdx.x;
    float m_g = -1e30f;
    for (int c = 0; c < NCH; ++c) m_g = fmaxf(m_g, pm[b * NCH + c]);
    float L = 0.f;
    for (int c = 0; c < NCH; ++c)
        L += pl[b * NCH + c] * __expf(pm[b * NCH + c] - m_g);
    const float inv = 1.f / L;
    float s = 0.f;
    for (int c = 0; c < NCH; ++c)
        s += pctx[((size_t)b * NCH + c) * A_ + t] * __expf(pm[b * NCH + c] - m_g);
    out[b * A_ + t] = s * inv;
}

// ---------------------------------------------------------------------------
extern "C" void kernel_launch(void* const* d_in, const int* in_sizes, int n_in,
                              void* d_out, int out_size, void* d_ws, size_t ws_size,
                              hipStream_t stream) {
    const float* enc  = (const float*)d_in[0];   // [B,S,2H] fp32
    const float* dh   = (const float*)d_in[1];   // [B,H]
    const int*   mks  = (const int*)  d_in[2];   // [B,S,1] bool->int
    const float* Wenc = (const float*)d_in[3];   // [2H,A]
    const float* benc = (const float*)d_in[4];   // [A]
    const float* Wdec = (const float*)d_in[5];   // [H,A]
    const float* bdec = (const float*)d_in[6];   // [A]
    const float* Watt = (const float*)d_in[7];   // [A]
    const float* batt = (const float*)d_in[8];   // [1]
    float* out = (float*)d_out;

    float* ws   = (float*)d_ws;
    float* pm   = ws;                             // 1024 f
    float* pl   = pm + B_ * NCH;                  // 1024 f
    float* pctx = pl + B_ * NCH;                  // 524288 f
    float* dp   = pctx + (size_t)B_ * NCH * A_;   // 131072 f
    bf16*  Whi  = (bf16*)(dp + 8 * B_ * A_);      // 1 MB
    bf16*  Wlo  = Whi + (size_t)A_ * E_;          // 1 MB
    (void)in_sizes; (void)n_in; (void)out_size; (void)ws_size;

    prep_kernel<<<384, 256, 0, stream>>>(Wenc, dh, Wdec, bdec, Whi, Wlo, dp);
    fused_kernel<<<B_ * NCH, 512, 0, stream>>>(
        enc, mks, Whi, Wlo, benc, Watt, batt, dp, pm, pl, pctx);
    combine_kernel<<<B_, 512, 0, stream>>>(pm, pl, pctx, out);
}

// Round 5
// 587.016 us; speedup vs baseline: 1.1285x; 1.1285x over previous
//
#include <hip/hip_runtime.h>
#include <math.h>

// Problem constants
#define B_  32
#define S_  2048
#define E_  1024   // 2*HIDDEN
#define A_  512    // ATT
#define H_  512

#define MB   128             // rows (s) per fused block
#define NCH  (S_ / MB)       // 16 chunks per batch row
#define KT   32              // K per step
#define NK   (E_ / KT)       // 32 K-iterations

typedef __bf16 bf16;
typedef __attribute__((ext_vector_type(8))) __bf16 bf16x8;
typedef __attribute__((ext_vector_type(4))) float  f32x4;

__device__ __forceinline__ float fast_tanh(float x) {
    x = fminf(fmaxf(x, -15.f), 15.f);
    const float e = __expf(2.f * x);
    return (e - 1.f) / (e + 1.f);
}

// ---------------------------------------------------------------------------
// prep kernel: blocks 0..127  : split W_enc into bf16 hi/lo, K-SLAB layout
//              blocks 128..383: dec_att k-split partials dp[seg][b][a]
// Slab layout: elem(a, k) -> (k>>5)*16384 + a*32 + (k&31)
//   i.e. [kt][a][32 k-elems]; per (a,kt) the 32 k values are contiguous 64 B.
//   A wave's 16-a x 64 B fragment loads coalesce into full cache lines, and
//   all 16 loads of one K-step share one base with <=3072 B imm offsets.
// ---------------------------------------------------------------------------
__global__ __launch_bounds__(256)
void prep_kernel(const float* __restrict__ Wenc,
                 const float* __restrict__ dh,
                 const float* __restrict__ Wdec,
                 const float* __restrict__ bdec,
                 bf16* __restrict__ Whi, bf16* __restrict__ Wlo,
                 float* __restrict__ dp) {
    const int t = threadIdx.x;
    if (blockIdx.x < 128) {
        __shared__ float tile[64][65];
        const int kb = blockIdx.x >> 3;      // 0..15
        const int ab = blockIdx.x & 7;       // 0..7
        const int k0 = kb * 64, a0 = ab * 64;
#pragma unroll
        for (int p = 0; p < 8; ++p) {
            const int kk = p * 8 + (t >> 5);
            const int aa = (t & 31) * 2;
            const float2 v = *(const float2*)&Wenc[(size_t)(k0 + kk) * A_ + a0 + aa];
            tile[kk][aa]     = v.x;
            tile[kk][aa + 1] = v.y;
        }
        __syncthreads();
        const int aa  = t >> 2;
        const int kk0 = (t & 3) * 16;
        bf16x8 hv0, hv1, lv0, lv1;
#pragma unroll
        for (int j = 0; j < 16; ++j) {
            const float x = tile[kk0 + j][aa];
            const bf16 h = (bf16)x;
            const bf16 l = (bf16)(x - (float)h);
            if (j < 8) { hv0[j] = h; lv0[j] = l; }
            else       { hv1[j - 8] = h; lv1[j - 8] = l; }
        }
        const int K0 = k0 + kk0;             // multiple of 16
        const size_t idx = (size_t)(K0 >> 5) * 16384 + (size_t)(a0 + aa) * 32 + (K0 & 31);
        bf16* dh_ = Whi + idx;
        bf16* dl_ = Wlo + idx;
        *(bf16x8*)dh_ = hv0; *((bf16x8*)dh_ + 1) = hv1;
        *(bf16x8*)dl_ = lv0; *((bf16x8*)dl_ + 1) = lv1;
    } else {
        __shared__ float dhl[64];
        const int idx = blockIdx.x - 128;
        const int b   = idx >> 3;
        const int seg = idx & 7;
        if (t < 64) dhl[t] = dh[b * H_ + seg * 64 + t];
        __syncthreads();
        const int a0 = t, a1 = t + 256;
        float acc0 = 0.f, acc1 = 0.f;
        const float* Wrow = Wdec + (size_t)(seg * 64) * A_;
#pragma unroll 8
        for (int h = 0; h < 64; ++h) {
            const float s = dhl[h];
            acc0 += s * Wrow[h * A_ + a0];
            acc1 += s * Wrow[h * A_ + a1];
        }
        if (seg == 0) { acc0 += bdec[a0]; acc1 += bdec[a1]; }
        dp[(size_t)(seg * B_ + b) * A_ + a0] = acc0;
        dp[(size_t)(seg * B_ + b) * A_ + a1] = acc1;
    }
}

// ---------------------------------------------------------------------------
// Fused kernel v5: BARRIER-FREE, LDS-FREE K-loop.
// 512 thr / 8 waves; wave (wr=wv>>2, wc=wv&3) owns rows [wr*64,+64) x cols
// [wc*128,+128): acc[4][8] = 128 AGPR. Per K-step each wave loads its own A
// rows global->reg (fp32, rows shared by 4 col-waves -> L1 hits), converts to
// bf16 hi/lo in-reg, loads W frags from the k-slab layout (base+imm offsets),
// and runs 96 MFMAs. No __syncthreads, no LDS, no inter-wave coupling in the
// loop: waves drift into natural anti-phase so MFMA/VALU/VMEM overlap across
// waves (m114) instead of summing as convoy phases. Dynamic K-loop
// (#pragma unroll 1) keeps the body ~2 KB -> I-cache resident.
// Register audit: acc 128 + ah/al 32 + bh/bl 32 + ptrs 24 + staging 32
// (transient) ~= 225 < 256 cap from __launch_bounds__(512,2).
// ---------------------------------------------------------------------------
__global__ __launch_bounds__(512, 2)
void fused_kernel(const float* __restrict__ enc,     // [B,S,E] fp32
                  const int*   __restrict__ masks,   // [B,S]
                  const bf16*  __restrict__ Whi_g,   // k-slab hi
                  const bf16*  __restrict__ Wlo_g,   // k-slab lo
                  const float* __restrict__ benc,    // [A]
                  const float* __restrict__ Watt,    // [A]
                  const float* __restrict__ batt,    // [1]
                  const float* __restrict__ dp,      // [8,B,A] dec_att parts
                  float* __restrict__ pm,            // [B*NCH]
                  float* __restrict__ pl,            // [B*NCH]
                  float* __restrict__ pctx) {        // [B*NCH, A]
    __shared__ struct {
        float decl[A_], wattl[A_], bencl[A_];     // 6 KB
        float red[MB][5];                         // 2.5 KB  score partials [row][wc]
        float ctxb[2][A_];                        // 4 KB    ctx partials [wr][col]
        float score[MB], p[MB];                   // 1 KB
        int   mask[MB];                           // 0.5 KB
    } sm;                                          // ~14 KB

    const int t    = threadIdx.x;
    const int wv   = t >> 6;      // wave 0..7
    const int L    = t & 63;      // lane
    const int quad = L >> 4;      // 0..3
    const int colL = L & 15;      // 0..15
    const int wr   = wv >> 2;     // 0..1  row-half
    const int wc   = wv & 3;      // 0..3  col-quarter
    const int b    = blockIdx.x >> 4;
    const int ch   = blockIdx.x & 15;
    const int s0   = ch * MB;

    const float* encB = enc + ((size_t)(b * S_ + s0)) * E_;

    f32x4 acc[4][8];   // [mt][nt]
#pragma unroll
    for (int mt = 0; mt < 4; ++mt)
#pragma unroll
        for (int nt = 0; nt < 8; ++nt) acc[mt][nt] = (f32x4){0.f, 0.f, 0.f, 0.f};

    // ---- per-lane A row pointers (fp32): row = wr*64 + mt*16 + colL, k-quad
    const float* a0p = encB + (size_t)(wr * 64 + colL) * E_ + quad * 8;
    const float* a1p = a0p + (size_t)16 * E_;
    const float* a2p = a0p + (size_t)32 * E_;
    const float* a3p = a0p + (size_t)48 * E_;

    // ---- per-lane W slab bases: a = wc*128 + (nt*16) + colL, elem = a*32+quad*8
    const bf16* wh0 = Whi_g + (size_t)(wc * 128 + colL) * 32 + quad * 8;
    const bf16* wh4 = wh0 + 2048;   // nt>=4 (a+64)
    const bf16* wl0 = Wlo_g + (size_t)(wc * 128 + colL) * 32 + quad * 8;
    const bf16* wl4 = wl0 + 2048;

#define CVT8(FA, FB, HV, LV)                                                   \
    {                                                                          \
        const float xs_[8] = {FA.x, FA.y, FA.z, FA.w, FB.x, FB.y, FB.z, FB.w}; \
        _Pragma("unroll")                                                      \
        for (int j_ = 0; j_ < 8; ++j_) {                                       \
            const bf16 h_ = (bf16)xs_[j_];                                     \
            HV[j_] = h_; LV[j_] = (bf16)(xs_[j_] - (float)h_);                 \
        }                                                                      \
    }

    // ================= K loop: dynamic, no barriers, no LDS =================
#pragma unroll 1
    for (int kt = 0; kt < NK; ++kt) {
        // A fp32 loads (this wave's 64 rows x 32 k)
        const float4 f0a = *(const float4*)(a0p), f0b = *(const float4*)(a0p + 4);
        const float4 f1a = *(const float4*)(a1p), f1b = *(const float4*)(a1p + 4);
        const float4 f2a = *(const float4*)(a2p), f2b = *(const float4*)(a2p + 4);
        const float4 f3a = *(const float4*)(a3p), f3b = *(const float4*)(a3p + 4);
        a0p += KT; a1p += KT; a2p += KT; a3p += KT;

        bf16x8 ah[4], al[4];
        CVT8(f0a, f0b, ah[0], al[0]);
        CVT8(f1a, f1b, ah[1], al[1]);
        CVT8(f2a, f2b, ah[2], al[2]);
        CVT8(f3a, f3b, ah[3], al[3]);

        {   // ---- nt 0..3
            bf16x8 bh[4], bl[4];
#pragma unroll
            for (int n = 0; n < 4; ++n) {
                bh[n] = *(const bf16x8*)(wh0 + n * 512);
                bl[n] = *(const bf16x8*)(wl0 + n * 512);
            }
            __builtin_amdgcn_s_setprio(1);
#pragma unroll
            for (int mt = 0; mt < 4; ++mt)
#pragma unroll
                for (int n = 0; n < 4; ++n) {
                    acc[mt][n] = __builtin_amdgcn_mfma_f32_16x16x32_bf16(ah[mt], bh[n], acc[mt][n], 0, 0, 0);
                    acc[mt][n] = __builtin_amdgcn_mfma_f32_16x16x32_bf16(al[mt], bh[n], acc[mt][n], 0, 0, 0);
                    acc[mt][n] = __builtin_amdgcn_mfma_f32_16x16x32_bf16(ah[mt], bl[n], acc[mt][n], 0, 0, 0);
                }
            __builtin_amdgcn_s_setprio(0);
        }
        {   // ---- nt 4..7
            bf16x8 bh[4], bl[4];
#pragma unroll
            for (int n = 0; n < 4; ++n) {
                bh[n] = *(const bf16x8*)(wh4 + n * 512);
                bl[n] = *(const bf16x8*)(wl4 + n * 512);
            }
            __builtin_amdgcn_s_setprio(1);
#pragma unroll
            for (int mt = 0; mt < 4; ++mt)
#pragma unroll
                for (int n = 0; n < 4; ++n) {
                    acc[mt][n + 4] = __builtin_amdgcn_mfma_f32_16x16x32_bf16(ah[mt], bh[n], acc[mt][n + 4], 0, 0, 0);
                    acc[mt][n + 4] = __builtin_amdgcn_mfma_f32_16x16x32_bf16(al[mt], bh[n], acc[mt][n + 4], 0, 0, 0);
                    acc[mt][n + 4] = __builtin_amdgcn_mfma_f32_16x16x32_bf16(ah[mt], bl[n], acc[mt][n + 4], 0, 0, 0);
                }
            __builtin_amdgcn_s_setprio(0);
        }
        wh0 += 16384; wh4 += 16384; wl0 += 16384; wl4 += 16384;
    }
#undef CVT8

    // ================= epilogue =================
    {
        float d = 0.f;
#pragma unroll
        for (int g = 0; g < 8; ++g) d += dp[(size_t)(g * B_ + b) * A_ + t];
        sm.decl[t]  = d;                 // t < 512 == A_
        sm.wattl[t] = Watt[t];
        sm.bencl[t] = benc[t];
        if (t < MB) sm.mask[t] = masks[(size_t)b * S_ + s0 + t];
    }
    __syncthreads();

    // scores: per-lane partial over this wave's 128 cols
    float sp[4][4];
#pragma unroll
    for (int mt = 0; mt < 4; ++mt)
#pragma unroll
        for (int r = 0; r < 4; ++r) sp[mt][r] = 0.f;

#pragma unroll
    for (int nt = 0; nt < 8; ++nt) {
        const int cg = wc * 128 + nt * 16 + colL;
        const float bv  = sm.bencl[cg];
        const float dv  = sm.decl[cg];
        const float wav = sm.wattl[cg];
#pragma unroll
        for (int mt = 0; mt < 4; ++mt)
#pragma unroll
            for (int r = 0; r < 4; ++r) {
                const float ea = acc[mt][nt][r] + bv;
                acc[mt][nt][r] = ea;
                sp[mt][r] += fast_tanh(ea + dv) * wav;
            }
    }
#pragma unroll
    for (int d = 1; d < 16; d <<= 1)
#pragma unroll
        for (int mt = 0; mt < 4; ++mt)
#pragma unroll
            for (int r = 0; r < 4; ++r)
                sp[mt][r] += __shfl_xor(sp[mt][r], d);
    if (colL == 0) {
#pragma unroll
        for (int mt = 0; mt < 4; ++mt)
#pragma unroll
            for (int r = 0; r < 4; ++r)
                sm.red[wr * 64 + mt * 16 + quad * 4 + r][wc] = sp[mt][r];
    }
    __syncthreads();

    if (t < MB) {
        float s = sm.red[t][0] + sm.red[t][1] + sm.red[t][2] + sm.red[t][3];
        sm.score[t] = s + batt[0];
    }
    __syncthreads();

    float m_loc = -1e30f;
    for (int r = 0; r < MB; ++r)
        if (!sm.mask[r]) m_loc = fmaxf(m_loc, sm.score[r]);
    if (t < MB) sm.p[t] = sm.mask[t] ? 0.f : __expf(sm.score[t] - m_loc);
    __syncthreads();

    // ctx: per-lane partial over this wave's 64 rows
    float ctxl[8];
#pragma unroll
    for (int nt = 0; nt < 8; ++nt) ctxl[nt] = 0.f;
#pragma unroll
    for (int mt = 0; mt < 4; ++mt)
#pragma unroll
        for (int r = 0; r < 4; ++r) {
            const float p = sm.p[wr * 64 + mt * 16 + quad * 4 + r];
#pragma unroll
            for (int nt = 0; nt < 8; ++nt) ctxl[nt] += p * acc[mt][nt][r];
        }
#pragma unroll
    for (int nt = 0; nt < 8; ++nt) {
        ctxl[nt] += __shfl_xor(ctxl[nt], 16);
        ctxl[nt] += __shfl_xor(ctxl[nt], 32);
    }
    if (quad == 0) {
#pragma unroll
        for (int nt = 0; nt < 8; ++nt)
            sm.ctxb[wr][wc * 128 + nt * 16 + colL] = ctxl[nt];
    }
    __syncthreads();

    pctx[(size_t)blockIdx.x * A_ + t] = sm.ctxb[0][t] + sm.ctxb[1][t];
    if (t == 0) {
        float l = 0.f;
        for (int r = 0; r < MB; ++r) l += sm.p[r];
        pm[blockIdx.x] = m_loc;
        pl[blockIdx.x] = l;
    }
}

// ---------------------------------------------------------------------------
// Combine: merge NCH chunk partials per batch row
// ---------------------------------------------------------------------------
__global__ __launch_bounds__(512)
void combine_kernel(const float* __restrict__ pm,
                    const float* __restrict__ pl,
                    const float* __restrict__ pctx,
                    float* __restrict__ out) {
    const int b = blockIdx.x;
    const int t = threadIdx.x;
    float m_g = -1e30f;
    for (int c = 0; c < NCH; ++c) m_g = fmaxf(m_g, pm[b * NCH + c]);
    float L = 0.f;
    for (int c = 0; c < NCH; ++c)
        L += pl[b * NCH + c] * __expf(pm[b * NCH + c] - m_g);
    const float inv = 1.f / L;
    float s = 0.f;
    for (int c = 0; c < NCH; ++c)
        s += pctx[((size_t)b * NCH + c) * A_ + t] * __expf(pm[b * NCH + c] - m_g);
    out[b * A_ + t] = s * inv;
}

// ---------------------------------------------------------------------------
extern "C" void kernel_launch(void* const* d_in, const int* in_sizes, int n_in,
                              void* d_out, int out_size, void* d_ws, size_t ws_size,
                              hipStream_t stream) {
    const float* enc  = (const float*)d_in[0];   // [B,S,2H] fp32
    const float* dh   = (const float*)d_in[1];   // [B,H]
    const int*   mks  = (const int*)  d_in[2];   // [B,S,1] bool->int
    const float* Wenc = (const float*)d_in[3];   // [2H,A]
    const float* benc = (const float*)d_in[4];   // [A]
    const float* Wdec = (const float*)d_in[5];   // [H,A]
    const float* bdec = (const float*)d_in[6];   // [A]
    const float* Watt = (const float*)d_in[7];   // [A]
    const float* batt = (const float*)d_in[8];   // [1]
    float* out = (float*)d_out;

    float* ws   = (float*)d_ws;
    float* pm   = ws;                             // 512 f
    float* pl   = pm + B_ * NCH;                  // 512 f
    float* pctx = pl + B_ * NCH;                  // 262144 f
    float* dp   = pctx + (size_t)B_ * NCH * A_;   // 131072 f
    bf16*  Whi  = (bf16*)(dp + 8 * B_ * A_);      // 1 MB (k-slab layout)
    bf16*  Wlo  = Whi + (size_t)A_ * E_;          // 1 MB (k-slab layout)
    (void)in_sizes; (void)n_in; (void)out_size; (void)ws_size;

    prep_kernel<<<384, 256, 0, stream>>>(Wenc, dh, Wdec, bdec, Whi, Wlo, dp);
    fused_kernel<<<B_ * NCH, 512, 0, stream>>>(
        enc, mks, Whi, Wlo, benc, Watt, batt, dp, pm, pl, pctx);
    combine_kernel<<<B_, 512, 0, stream>>>(pm, pl, pctx, out);
}